// Round 1
// baseline (1532.443 us; speedup 1.0000x reference)
//
#include <hip/hip_runtime.h>

constexpr float BN_EPS = 1e-5f;

__device__ __forceinline__ float4 ld4(const float* p) { return *(const float4*)p; }
__device__ __forceinline__ void fma4(float4& a, const float4 w, const float f) {
  a.x = fmaf(w.x, f, a.x); a.y = fmaf(w.y, f, a.y);
  a.z = fmaf(w.z, f, a.z); a.w = fmaf(w.w, f, a.w);
}
__device__ __forceinline__ void relu4(float4& a) {
  a.x = fmaxf(a.x, 0.f); a.y = fmaxf(a.y, 0.f);
  a.z = fmaxf(a.z, 0.f); a.w = fmaxf(a.w, 0.f);
}

// ---------------- CSR build ----------------
__global__ void hist_kernel(const int* __restrict__ dst, int E, int* __restrict__ deg) {
  int e = blockIdx.x * 256 + threadIdx.x;
  if (e < E) atomicAdd(&deg[dst[e]], 1);
}

__global__ void scan_kernel(const int* __restrict__ deg, int n,
                            int* __restrict__ off, int* __restrict__ cur) {
  __shared__ int lds[1024];
  __shared__ int carry_s;
  if (threadIdx.x == 0) carry_s = 0;
  __syncthreads();
  for (int base = 0; base < n; base += 1024) {
    int i = base + threadIdx.x;
    int v = (i < n) ? deg[i] : 0;
    lds[threadIdx.x] = v;
    __syncthreads();
    for (int s = 1; s < 1024; s <<= 1) {
      int t = (threadIdx.x >= s) ? lds[threadIdx.x - s] : 0;
      __syncthreads();
      lds[threadIdx.x] += t;
      __syncthreads();
    }
    int inc = lds[threadIdx.x];   // inclusive scan of this chunk
    int c = carry_s;
    __syncthreads();
    if (i < n) { int o = c + inc - v; off[i] = o; cur[i] = o; }
    if (threadIdx.x == 1023) carry_s = c + inc;
    __syncthreads();
  }
}

__global__ void fill_kernel(const int* __restrict__ src, const int* __restrict__ dst, int E,
                            int* __restrict__ cur, int* __restrict__ elist) {
  int e = blockIdx.x * 256 + threadIdx.x;
  if (e < E) {
    int p = atomicAdd(&cur[dst[e]], 1);
    elist[p] = src[e];
  }
}

// ---------------- node projection: OUT[n][0..127] = act(X[n]) @ [Wa;Wb]^T ----------------
// Wa supplies output cols 0..63 (row o at Wa + o*lda + koffa), Wb cols 64..127.
// If BN: x -> relu(scale[k]*x + shift[k]) applied on LDS load.
template <int K, bool BN>
__global__ __launch_bounds__(256) void proj_kernel(
    const float* __restrict__ X,
    const float* __restrict__ Wa, int lda, int koffa,
    const float* __restrict__ Wb, int ldb, int koffb,
    const float* __restrict__ scale, const float* __restrict__ shift,
    float* __restrict__ OUT, int n) {
  __shared__ alignas(16) float xs[8][K];
  int nb = blockIdx.x * 8;
  for (int idx = threadIdx.x; idx < 8 * K; idx += 256) {
    int nl = idx / K, k = idx - nl * K;
    int node = nb + nl;
    float v = (node < n) ? X[(size_t)node * K + k] : 0.f;
    if (BN) v = fmaxf(fmaf(v, scale[k], shift[k]), 0.f);
    xs[nl][k] = v;
  }
  __syncthreads();
  int nl = threadIdx.x >> 5;      // 0..7
  int og = threadIdx.x & 31;      // 0..31 -> 4 consecutive outputs
  int node = nb + nl;
  const float* wp; int ld;
  if (og < 16) { wp = Wa + (og * 4) * lda + koffa; ld = lda; }
  else         { wp = Wb + (og * 4 - 64) * ldb + koffb; ld = ldb; }
  float a0 = 0.f, a1 = 0.f, a2 = 0.f, a3 = 0.f;
#pragma unroll
  for (int k4 = 0; k4 < K / 4; ++k4) {
    float4 xv = ld4(&xs[nl][k4 * 4]);
    const float* w = wp + k4 * 4;
    float4 w0 = ld4(w);
    float4 w1 = ld4(w + ld);
    float4 w2 = ld4(w + 2 * ld);
    float4 w3 = ld4(w + 3 * ld);
    a0 = fmaf(xv.x, w0.x, fmaf(xv.y, w0.y, fmaf(xv.z, w0.z, fmaf(xv.w, w0.w, a0))));
    a1 = fmaf(xv.x, w1.x, fmaf(xv.y, w1.y, fmaf(xv.z, w1.z, fmaf(xv.w, w1.w, a1))));
    a2 = fmaf(xv.x, w2.x, fmaf(xv.y, w2.y, fmaf(xv.z, w2.z, fmaf(xv.w, w2.w, a2))));
    a3 = fmaf(xv.x, w3.x, fmaf(xv.y, w3.y, fmaf(xv.z, w3.z, fmaf(xv.w, w3.w, a3))));
  }
  if (node < n) {
    float4 r = make_float4(a0, a1, a2, a3);
    *(float4*)&OUT[(size_t)node * 128 + og * 4] = r;
  }
}

// ---------------- aggregation: HP[i][c] = segmean + bl[c] + xr[i][c] ----------------
// P: [N,128], cols 0..63 = projected message (y), cols 64..127 = lin_r part (xr)
__global__ __launch_bounds__(256) void agg_kernel(
    const float* __restrict__ P, const int* __restrict__ off, const int* __restrict__ deg,
    const int* __restrict__ elist, const float* __restrict__ bl,
    float* __restrict__ HP, int n) {
  int node = blockIdx.x * 4 + (threadIdx.x >> 6);
  if (node >= n) return;
  int c = threadIdx.x & 63;
  int d = deg[node];
  int o = off[node];
  float a0 = 0.f, a1 = 0.f, a2 = 0.f, a3 = 0.f;
  int j = 0;
  for (; j + 4 <= d; j += 4) {
    int s0 = elist[o + j], s1 = elist[o + j + 1], s2 = elist[o + j + 2], s3 = elist[o + j + 3];
    a0 += P[(size_t)s0 * 128 + c];
    a1 += P[(size_t)s1 * 128 + c];
    a2 += P[(size_t)s2 * 128 + c];
    a3 += P[(size_t)s3 * 128 + c];
  }
  for (; j < d; ++j) a0 += P[(size_t)elist[o + j] * 128 + c];
  float acc = (a0 + a1) + (a2 + a3);
  float agg = acc / (float)(d > 0 ? d : 1);
  HP[(size_t)node * 64 + c] = agg + bl[c] + P[(size_t)node * 128 + 64 + c];
}

// ---------------- BN statistics ----------------
__global__ __launch_bounds__(256) void stats_kernel(const float* __restrict__ HP, int n,
                                                    float* __restrict__ partials) {
  int c = threadIdx.x & 63;
  int r0 = blockIdx.x * 4 + (threadIdx.x >> 6);
  float s = 0.f, q = 0.f;
  for (int i = r0; i < n; i += 1024) {
    float v = HP[(size_t)i * 64 + c];
    s += v; q += v * v;
  }
  __shared__ float ls[256], lq[256];
  ls[threadIdx.x] = s; lq[threadIdx.x] = q;
  __syncthreads();
  if (threadIdx.x < 64) {
    s = ls[threadIdx.x] + ls[threadIdx.x + 64] + ls[threadIdx.x + 128] + ls[threadIdx.x + 192];
    q = lq[threadIdx.x] + lq[threadIdx.x + 64] + lq[threadIdx.x + 128] + lq[threadIdx.x + 192];
    partials[blockIdx.x * 128 + c] = s;
    partials[blockIdx.x * 128 + 64 + c] = q;
  }
}

__global__ void bn_finalize_kernel(const float* __restrict__ partials, int nblk, int n,
                                   const float* __restrict__ g, const float* __restrict__ be,
                                   float* __restrict__ scale, float* __restrict__ shift) {
  int c = threadIdx.x;  // 64 threads
  float s = 0.f, q = 0.f;
  for (int b = 0; b < nblk; ++b) { s += partials[b * 128 + c]; q += partials[b * 128 + 64 + c]; }
  float mean = s / (float)n;
  float var = q / (float)n - mean * mean;
  float sc = g[c] * rsqrtf(var + BN_EPS);
  scale[c] = sc;
  shift[c] = be[c] - mean * sc;
}

// ---------------- Dte[t][o] = bm1[o] + sum_k Wm1[o][144+k]*temb[t][k] ----------------
__global__ void dte_kernel(const float* __restrict__ Wm1, const float* __restrict__ temb,
                           const float* __restrict__ bm1, float* __restrict__ Dte) {
  int t = threadIdx.x >> 6, o = threadIdx.x & 63;  // 1024 threads
  float acc = bm1[o];
#pragma unroll
  for (int k = 0; k < 8; ++k) acc = fmaf(Wm1[o * 152 + 144 + k], temb[t * 8 + k], acc);
  Dte[t * 64 + o] = acc;
}

// ---------------- fused edge MLP ----------------
__global__ __launch_bounds__(256) void edge_kernel(
    const float* __restrict__ UV, const int* __restrict__ ei,
    const float* __restrict__ eattr, const int* __restrict__ tix,
    const float* __restrict__ Dte,
    const float* __restrict__ Wm1, const float* __restrict__ Wm2,
    const float* __restrict__ bm2, const float* __restrict__ Wm3,
    const float* __restrict__ bm3, float* __restrict__ out, int E) {
  __shared__ alignas(16) float CwT[16][64];    // Wm1[:,128:144] transposed
  __shared__ alignas(16) float W2T[64][32];    // Wm2 transposed
  __shared__ alignas(16) float DteS[16 * 68];  // pitch 68 to spread banks
  __shared__ alignas(16) float W3S[64];
  __shared__ float bm2S[32];
  __shared__ float bm3S[2];
  for (int idx = threadIdx.x; idx < 1024; idx += 256) {
    int k = idx >> 6, o = idx & 63;
    CwT[k][o] = Wm1[o * 152 + 128 + k];
    DteS[k * 68 + o] = Dte[idx];               // here k plays the role of t
  }
  for (int idx = threadIdx.x; idx < 2048; idx += 256) {
    int k = idx >> 5, jj = idx & 31;
    W2T[k][jj] = Wm2[jj * 64 + k];
  }
  if (threadIdx.x < 64) W3S[threadIdx.x] = Wm3[threadIdx.x];
  if (threadIdx.x < 32) bm2S[threadIdx.x] = bm2[threadIdx.x];
  if (threadIdx.x < 2) bm3S[threadIdx.x] = bm3[threadIdx.x];
  __syncthreads();

  int e = blockIdx.x * 256 + threadIdx.x;
  if (e >= E) return;
  int s = ei[e], d = ei[E + e], t = tix[e];

  float ea[16];
#pragma unroll
  for (int q = 0; q < 4; ++q) {
    float4 v = ld4(&eattr[(size_t)e * 16 + q * 4]);
    ea[q * 4 + 0] = v.x; ea[q * 4 + 1] = v.y; ea[q * 4 + 2] = v.z; ea[q * 4 + 3] = v.w;
  }
  const float* up = UV + (size_t)s * 128;
  const float* vp = UV + (size_t)d * 128 + 64;

  float4 z1v[16];
#pragma unroll
  for (int o4 = 0; o4 < 16; ++o4) {
    float4 uu = ld4(&up[o4 * 4]);
    float4 vv = ld4(&vp[o4 * 4]);
    float4 dd = ld4(&DteS[t * 68 + o4 * 4]);
    z1v[o4].x = uu.x + vv.x + dd.x;
    z1v[o4].y = uu.y + vv.y + dd.y;
    z1v[o4].z = uu.z + vv.z + dd.z;
    z1v[o4].w = uu.w + vv.w + dd.w;
  }
#pragma unroll
  for (int k = 0; k < 16; ++k) {
    float f = ea[k];
#pragma unroll
    for (int o4 = 0; o4 < 16; ++o4) {
      float4 wv = ld4(&CwT[k][o4 * 4]);
      fma4(z1v[o4], wv, f);
    }
  }
#pragma unroll
  for (int o4 = 0; o4 < 16; ++o4) relu4(z1v[o4]);

  float4 z2v[8];
#pragma unroll
  for (int j4 = 0; j4 < 8; ++j4) {
    z2v[j4].x = bm2S[j4 * 4 + 0]; z2v[j4].y = bm2S[j4 * 4 + 1];
    z2v[j4].z = bm2S[j4 * 4 + 2]; z2v[j4].w = bm2S[j4 * 4 + 3];
  }
#pragma unroll
  for (int k4 = 0; k4 < 16; ++k4) {
    float4 fz = z1v[k4];
#pragma unroll
    for (int j4 = 0; j4 < 8; ++j4) {
      float4 w0 = ld4(&W2T[k4 * 4 + 0][j4 * 4]);
      float4 w1 = ld4(&W2T[k4 * 4 + 1][j4 * 4]);
      float4 w2 = ld4(&W2T[k4 * 4 + 2][j4 * 4]);
      float4 w3 = ld4(&W2T[k4 * 4 + 3][j4 * 4]);
      fma4(z2v[j4], w0, fz.x);
      fma4(z2v[j4], w1, fz.y);
      fma4(z2v[j4], w2, fz.z);
      fma4(z2v[j4], w3, fz.w);
    }
  }
#pragma unroll
  for (int j4 = 0; j4 < 8; ++j4) relu4(z2v[j4]);

  float o0 = bm3S[0], o1 = bm3S[1];
#pragma unroll
  for (int k4 = 0; k4 < 8; ++k4) {
    float4 fz = z2v[k4];
    float4 wa = ld4(&W3S[k4 * 4]);
    float4 wb = ld4(&W3S[32 + k4 * 4]);
    o0 = fmaf(fz.x, wa.x, o0); o0 = fmaf(fz.y, wa.y, o0);
    o0 = fmaf(fz.z, wa.z, o0); o0 = fmaf(fz.w, wa.w, o0);
    o1 = fmaf(fz.x, wb.x, o1); o1 = fmaf(fz.y, wb.y, o1);
    o1 = fmaf(fz.z, wb.z, o1); o1 = fmaf(fz.w, wb.w, o1);
  }
  *(float2*)&out[(size_t)e * 2] = make_float2(o0, o1);
}

// ---------------- launcher ----------------
extern "C" void kernel_launch(void* const* d_in, const int* in_sizes, int n_in,
                              void* d_out, int out_size, void* d_ws, size_t ws_size,
                              hipStream_t stream) {
  const float* x    = (const float*)d_in[0];
  const int*   ei   = (const int*)d_in[1];
  const float* ea   = (const float*)d_in[2];
  const int*   tix  = (const int*)d_in[3];
  const float* temb = (const float*)d_in[4];
  const float* W1l  = (const float*)d_in[5];
  const float* b1l  = (const float*)d_in[6];
  const float* W1r  = (const float*)d_in[7];
  const float* g1   = (const float*)d_in[8];
  const float* be1  = (const float*)d_in[9];
  const float* W2l  = (const float*)d_in[10];
  const float* b2l  = (const float*)d_in[11];
  const float* W2r  = (const float*)d_in[12];
  const float* g2   = (const float*)d_in[13];
  const float* be2  = (const float*)d_in[14];
  const float* Wm1  = (const float*)d_in[15];
  const float* bm1  = (const float*)d_in[16];
  const float* Wm2  = (const float*)d_in[17];
  const float* bm2  = (const float*)d_in[18];
  const float* Wm3  = (const float*)d_in[19];
  const float* bm3  = (const float*)d_in[20];
  float* out = (float*)d_out;

  const int N = in_sizes[0] / 128;
  const int E = in_sizes[3];

  char* w = (char*)d_ws;
  auto alloc = [&](size_t bytes) -> char* {
    char* p = w;
    w += (bytes + 255) & ~(size_t)255;
    return p;
  };
  int* deg      = (int*)alloc((size_t)N * 4);
  int* off      = (int*)alloc((size_t)(N + 1) * 4);
  int* cur      = (int*)alloc((size_t)N * 4);
  int* elist    = (int*)alloc((size_t)E * 4);
  float* P      = (float*)alloc((size_t)N * 128 * 4);  // also reused as UV
  float* HP     = (float*)alloc((size_t)N * 64 * 4);   // hpre1 then hpre2
  float* partials = (float*)alloc(256 * 128 * 4);
  float* sc1 = (float*)alloc(64 * 4);
  float* sh1 = (float*)alloc(64 * 4);
  float* sc2 = (float*)alloc(64 * 4);
  float* sh2 = (float*)alloc(64 * 4);
  float* Dte = (float*)alloc(16 * 64 * 4);

  const int* srcp = ei;
  const int* dstp = ei + E;

  int eb = (E + 255) / 256;
  int nb8 = (N + 7) / 8;
  int nb4 = (N + 3) / 4;

  // CSR build (shared by both SAGE layers)
  hipMemsetAsync(deg, 0, (size_t)N * 4, stream);
  hipLaunchKernelGGL(hist_kernel, dim3(eb), dim3(256), 0, stream, dstp, E, deg);
  hipLaunchKernelGGL(scan_kernel, dim3(1), dim3(1024), 0, stream, deg, N, off, cur);
  hipLaunchKernelGGL(fill_kernel, dim3(eb), dim3(256), 0, stream, srcp, dstp, E, cur, elist);

  // ---- SAGE layer 1 ----
  hipLaunchKernelGGL((proj_kernel<128, false>), dim3(nb8), dim3(256), 0, stream,
                     x, W1l, 128, 0, W1r, 128, 0, (const float*)nullptr, (const float*)nullptr, P, N);
  hipLaunchKernelGGL(agg_kernel, dim3(nb4), dim3(256), 0, stream, P, off, deg, elist, b1l, HP, N);
  hipLaunchKernelGGL(stats_kernel, dim3(256), dim3(256), 0, stream, HP, N, partials);
  hipLaunchKernelGGL(bn_finalize_kernel, dim3(1), dim3(64), 0, stream, partials, 256, N, g1, be1, sc1, sh1);

  // ---- SAGE layer 2 (BN1+relu fused into projection load) ----
  hipLaunchKernelGGL((proj_kernel<64, true>), dim3(nb8), dim3(256), 0, stream,
                     HP, W2l, 64, 0, W2r, 64, 0, sc1, sh1, P, N);
  hipLaunchKernelGGL(agg_kernel, dim3(nb4), dim3(256), 0, stream, P, off, deg, elist, b2l, HP, N);
  hipLaunchKernelGGL(stats_kernel, dim3(256), dim3(256), 0, stream, HP, N, partials);
  hipLaunchKernelGGL(bn_finalize_kernel, dim3(1), dim3(64), 0, stream, partials, 256, N, g2, be2, sc2, sh2);

  // ---- u/v node precompute: u = Wm1[:, :64] @ h2, v = Wm1[:, 64:128] @ h2 ----
  hipLaunchKernelGGL((proj_kernel<64, true>), dim3(nb8), dim3(256), 0, stream,
                     HP, Wm1, 152, 0, Wm1, 152, 64, sc2, sh2, P, N);
  hipLaunchKernelGGL(dte_kernel, dim3(1), dim3(1024), 0, stream, Wm1, temb, bm1, Dte);

  // ---- fused edge MLP ----
  hipLaunchKernelGGL(edge_kernel, dim3(eb), dim3(256), 0, stream,
                     P, ei, ea, tix, Dte, Wm1, Wm2, bm2, Wm3, bm3, out, E);
}

// Round 2
// 870.971 us; speedup vs baseline: 1.7595x; 1.7595x over previous
//
#include <hip/hip_runtime.h>

constexpr float BN_EPS = 1e-5f;

__device__ __forceinline__ float4 ld4(const float* p) { return *(const float4*)p; }
__device__ __forceinline__ void fma4(float4& a, const float4 w, const float f) {
  a.x = fmaf(w.x, f, a.x); a.y = fmaf(w.y, f, a.y);
  a.z = fmaf(w.z, f, a.z); a.w = fmaf(w.w, f, a.w);
}
__device__ __forceinline__ void relu4(float4& a) {
  a.x = fmaxf(a.x, 0.f); a.y = fmaxf(a.y, 0.f);
  a.z = fmaxf(a.z, 0.f); a.w = fmaxf(a.w, 0.f);
}

// ---------------- CSR build ----------------
__global__ void hist_kernel(const int* __restrict__ dst, int E, int* __restrict__ deg) {
  int e = blockIdx.x * 256 + threadIdx.x;
  if (e < E) atomicAdd(&deg[dst[e]], 1);
}

// 3-phase exclusive scan: block scan -> wave scan of block sums -> add base
__global__ __launch_bounds__(1024) void scan_blocks_kernel(const int* __restrict__ deg, int n,
                                                           int* __restrict__ off, int* __restrict__ bsum) {
  __shared__ int lds[1024];
  int i = blockIdx.x * 1024 + threadIdx.x;
  int v = (i < n) ? deg[i] : 0;
  lds[threadIdx.x] = v;
  __syncthreads();
  for (int s = 1; s < 1024; s <<= 1) {
    int t = (threadIdx.x >= (unsigned)s) ? lds[threadIdx.x - s] : 0;
    __syncthreads();
    lds[threadIdx.x] += t;
    __syncthreads();
  }
  if (i < n) off[i] = lds[threadIdx.x] - v;      // exclusive within block
  if (threadIdx.x == 1023) bsum[blockIdx.x] = lds[1023];
}

__global__ void scan_sums_kernel(int* __restrict__ bsum, int nb) {
  int carry = 0;
  for (int base = 0; base < nb; base += 64) {
    int l = base + (int)threadIdx.x;
    int orig = (l < nb) ? bsum[l] : 0;
    int v = orig;
    for (int s = 1; s < 64; s <<= 1) {
      int t = __shfl_up(v, s);
      if ((int)threadIdx.x >= s) v += t;
    }
    if (l < nb) bsum[l] = carry + v - orig;      // exclusive across blocks
    carry += __shfl(v, 63);
  }
}

__global__ __launch_bounds__(1024) void scan_add_kernel(const int* __restrict__ bsum, int n,
                                                        int* __restrict__ off, int* __restrict__ cur) {
  int i = blockIdx.x * 1024 + threadIdx.x;
  if (i < n) {
    int o = off[i] + bsum[blockIdx.x];
    off[i] = o;
    cur[i] = o;
  }
}

__global__ void fill_kernel(const int* __restrict__ src, const int* __restrict__ dst, int E,
                            int* __restrict__ cur, int* __restrict__ elist) {
  int e = blockIdx.x * 256 + threadIdx.x;
  if (e < E) {
    int p = atomicAdd(&cur[dst[e]], 1);
    elist[p] = src[e];
  }
}

// ---------------- node projection v2: LDS-tiled GEMM ----------------
// Block tile: 64 nodes x 64 outputs. blockIdx.y selects output half:
//   ob=0 -> cols 0..63 from Wa (row o at Wa + o*lda + koffa)
//   ob=1 -> cols 64..127 from Wb
// Thread tile: 4 nodes x 4 outputs (outputs interleaved at stride 16 for bank spread).
// If BN: x -> relu(scale[k]*x + shift[k]) applied on LDS load.
template <int K, bool BN>
__global__ __launch_bounds__(256) void proj2_kernel(
    const float* __restrict__ X,
    const float* __restrict__ Wa, int lda, int koffa,
    const float* __restrict__ Wb, int ldb, int koffb,
    const float* __restrict__ scale, const float* __restrict__ shift,
    float* __restrict__ OUT, int n) {
  constexpr int KP = K + 4;                      // pitch: +4 floats keeps 16B align, spreads banks
  __shared__ alignas(16) float ws[64 * KP];
  __shared__ alignas(16) float xs[64 * KP];
  const int ob = blockIdx.y;
  const float* W = ob ? Wb : Wa;
  const int ld = ob ? ldb : lda;
  const int koff = ob ? koffb : koffa;

  for (int idx = threadIdx.x; idx < 64 * K; idx += 256) {
    int o = idx / K, k = idx - o * K;
    ws[o * KP + k] = W[o * ld + koff + k];
  }
  int nb = blockIdx.x * 64;
  for (int idx = threadIdx.x; idx < 64 * K; idx += 256) {
    int nl = idx / K, k = idx - nl * K;
    int node = nb + nl;
    float v = (node < n) ? X[(size_t)node * K + k] : 0.f;
    if (BN) v = fmaxf(fmaf(v, scale[k], shift[k]), 0.f);
    xs[nl * KP + k] = v;
  }
  __syncthreads();

  int ng = threadIdx.x >> 4;    // 0..15 -> nodes ng*4 .. ng*4+3
  int og = threadIdx.x & 15;    // 0..15 -> outputs og + 16*j, j=0..3
  float acc[4][4];
#pragma unroll
  for (int i = 0; i < 4; ++i)
#pragma unroll
    for (int j = 0; j < 4; ++j) acc[i][j] = 0.f;

  const float* xp = xs + (ng * 4) * KP;
  const float* wp = ws + og * KP;
#pragma unroll 2
  for (int k4 = 0; k4 < K / 4; ++k4) {
    float4 xv[4];
#pragma unroll
    for (int i = 0; i < 4; ++i) xv[i] = ld4(xp + i * KP + k4 * 4);
#pragma unroll
    for (int j = 0; j < 4; ++j) {
      float4 wv = ld4(wp + (j * 16) * KP + k4 * 4);
#pragma unroll
      for (int i = 0; i < 4; ++i) {
        acc[i][j] = fmaf(xv[i].x, wv.x, acc[i][j]);
        acc[i][j] = fmaf(xv[i].y, wv.y, acc[i][j]);
        acc[i][j] = fmaf(xv[i].z, wv.z, acc[i][j]);
        acc[i][j] = fmaf(xv[i].w, wv.w, acc[i][j]);
      }
    }
  }

#pragma unroll
  for (int i = 0; i < 4; ++i) {
    int node = nb + ng * 4 + i;
    if (node < n) {
#pragma unroll
      for (int j = 0; j < 4; ++j)
        OUT[(size_t)node * 128 + ob * 64 + j * 16 + og] = acc[i][j];
    }
  }
}

// ---------------- aggregation: HP[i][c] = segmean + bl[c] + xr[i][c] ----------------
// P: [N,128], cols 0..63 = projected message (y), cols 64..127 = lin_r part (xr)
__global__ __launch_bounds__(256) void agg_kernel(
    const float* __restrict__ P, const int* __restrict__ off, const int* __restrict__ deg,
    const int* __restrict__ elist, const float* __restrict__ bl,
    float* __restrict__ HP, int n) {
  int node = blockIdx.x * 4 + (threadIdx.x >> 6);
  if (node >= n) return;
  int c = threadIdx.x & 63;
  int d = deg[node];
  int o = off[node];
  float a0 = 0.f, a1 = 0.f, a2 = 0.f, a3 = 0.f;
  int j = 0;
  for (; j + 4 <= d; j += 4) {
    int s0 = elist[o + j], s1 = elist[o + j + 1], s2 = elist[o + j + 2], s3 = elist[o + j + 3];
    a0 += P[(size_t)s0 * 128 + c];
    a1 += P[(size_t)s1 * 128 + c];
    a2 += P[(size_t)s2 * 128 + c];
    a3 += P[(size_t)s3 * 128 + c];
  }
  for (; j < d; ++j) a0 += P[(size_t)elist[o + j] * 128 + c];
  float acc = (a0 + a1) + (a2 + a3);
  float agg = acc / (float)(d > 0 ? d : 1);
  HP[(size_t)node * 64 + c] = agg + bl[c] + P[(size_t)node * 128 + 64 + c];
}

// ---------------- BN statistics ----------------
__global__ __launch_bounds__(256) void stats_kernel(const float* __restrict__ HP, int n,
                                                    float* __restrict__ partials) {
  int c = threadIdx.x & 63;
  int r0 = blockIdx.x * 4 + (threadIdx.x >> 6);
  float s = 0.f, q = 0.f;
  for (int i = r0; i < n; i += 1024) {
    float v = HP[(size_t)i * 64 + c];
    s += v; q += v * v;
  }
  __shared__ float ls[256], lq[256];
  ls[threadIdx.x] = s; lq[threadIdx.x] = q;
  __syncthreads();
  if (threadIdx.x < 64) {
    s = ls[threadIdx.x] + ls[threadIdx.x + 64] + ls[threadIdx.x + 128] + ls[threadIdx.x + 192];
    q = lq[threadIdx.x] + lq[threadIdx.x + 64] + lq[threadIdx.x + 128] + lq[threadIdx.x + 192];
    partials[blockIdx.x * 128 + c] = s;
    partials[blockIdx.x * 128 + 64 + c] = q;
  }
}

__global__ void bn_finalize_kernel(const float* __restrict__ partials, int nblk, int n,
                                   const float* __restrict__ g, const float* __restrict__ be,
                                   float* __restrict__ scale, float* __restrict__ shift) {
  int c = threadIdx.x;  // 64 threads
  float s = 0.f, q = 0.f;
  for (int b = 0; b < nblk; ++b) { s += partials[b * 128 + c]; q += partials[b * 128 + 64 + c]; }
  float mean = s / (float)n;
  float var = q / (float)n - mean * mean;
  float sc = g[c] * rsqrtf(var + BN_EPS);
  scale[c] = sc;
  shift[c] = be[c] - mean * sc;
}

// ---------------- Dte[t][o] = bm1[o] + sum_k Wm1[o][144+k]*temb[t][k] ----------------
__global__ void dte_kernel(const float* __restrict__ Wm1, const float* __restrict__ temb,
                           const float* __restrict__ bm1, float* __restrict__ Dte) {
  int t = threadIdx.x >> 6, o = threadIdx.x & 63;  // 1024 threads
  float acc = bm1[o];
#pragma unroll
  for (int k = 0; k < 8; ++k) acc = fmaf(Wm1[o * 152 + 144 + k], temb[t * 8 + k], acc);
  Dte[t * 64 + o] = acc;
}

// ---------------- fused edge MLP ----------------
__global__ __launch_bounds__(256) void edge_kernel(
    const float* __restrict__ UV, const int* __restrict__ ei,
    const float* __restrict__ eattr, const int* __restrict__ tix,
    const float* __restrict__ Dte,
    const float* __restrict__ Wm1, const float* __restrict__ Wm2,
    const float* __restrict__ bm2, const float* __restrict__ Wm3,
    const float* __restrict__ bm3, float* __restrict__ out, int E) {
  __shared__ alignas(16) float CwT[16][64];    // Wm1[:,128:144] transposed
  __shared__ alignas(16) float W2T[64][32];    // Wm2 transposed
  __shared__ alignas(16) float DteS[16 * 68];  // pitch 68 to spread banks
  __shared__ alignas(16) float W3S[64];
  __shared__ float bm2S[32];
  __shared__ float bm3S[2];
  for (int idx = threadIdx.x; idx < 1024; idx += 256) {
    int k = idx >> 6, o = idx & 63;
    CwT[k][o] = Wm1[o * 152 + 128 + k];
    DteS[k * 68 + o] = Dte[idx];               // here k plays the role of t
  }
  for (int idx = threadIdx.x; idx < 2048; idx += 256) {
    int k = idx >> 5, jj = idx & 31;
    W2T[k][jj] = Wm2[jj * 64 + k];
  }
  if (threadIdx.x < 64) W3S[threadIdx.x] = Wm3[threadIdx.x];
  if (threadIdx.x < 32) bm2S[threadIdx.x] = bm2[threadIdx.x];
  if (threadIdx.x < 2) bm3S[threadIdx.x] = bm3[threadIdx.x];
  __syncthreads();

  int e = blockIdx.x * 256 + threadIdx.x;
  if (e >= E) return;
  int s = ei[e], d = ei[E + e], t = tix[e];

  float ea[16];
#pragma unroll
  for (int q = 0; q < 4; ++q) {
    float4 v = ld4(&eattr[(size_t)e * 16 + q * 4]);
    ea[q * 4 + 0] = v.x; ea[q * 4 + 1] = v.y; ea[q * 4 + 2] = v.z; ea[q * 4 + 3] = v.w;
  }
  const float* up = UV + (size_t)s * 128;
  const float* vp = UV + (size_t)d * 128 + 64;

  float4 z1v[16];
#pragma unroll
  for (int o4 = 0; o4 < 16; ++o4) {
    float4 uu = ld4(&up[o4 * 4]);
    float4 vv = ld4(&vp[o4 * 4]);
    float4 dd = ld4(&DteS[t * 68 + o4 * 4]);
    z1v[o4].x = uu.x + vv.x + dd.x;
    z1v[o4].y = uu.y + vv.y + dd.y;
    z1v[o4].z = uu.z + vv.z + dd.z;
    z1v[o4].w = uu.w + vv.w + dd.w;
  }
#pragma unroll
  for (int k = 0; k < 16; ++k) {
    float f = ea[k];
#pragma unroll
    for (int o4 = 0; o4 < 16; ++o4) {
      float4 wv = ld4(&CwT[k][o4 * 4]);
      fma4(z1v[o4], wv, f);
    }
  }
#pragma unroll
  for (int o4 = 0; o4 < 16; ++o4) relu4(z1v[o4]);

  float4 z2v[8];
#pragma unroll
  for (int j4 = 0; j4 < 8; ++j4) {
    z2v[j4].x = bm2S[j4 * 4 + 0]; z2v[j4].y = bm2S[j4 * 4 + 1];
    z2v[j4].z = bm2S[j4 * 4 + 2]; z2v[j4].w = bm2S[j4 * 4 + 3];
  }
#pragma unroll
  for (int k4 = 0; k4 < 16; ++k4) {
    float4 fz = z1v[k4];
#pragma unroll
    for (int j4 = 0; j4 < 8; ++j4) {
      float4 w0 = ld4(&W2T[k4 * 4 + 0][j4 * 4]);
      float4 w1 = ld4(&W2T[k4 * 4 + 1][j4 * 4]);
      float4 w2 = ld4(&W2T[k4 * 4 + 2][j4 * 4]);
      float4 w3 = ld4(&W2T[k4 * 4 + 3][j4 * 4]);
      fma4(z2v[j4], w0, fz.x);
      fma4(z2v[j4], w1, fz.y);
      fma4(z2v[j4], w2, fz.z);
      fma4(z2v[j4], w3, fz.w);
    }
  }
#pragma unroll
  for (int j4 = 0; j4 < 8; ++j4) relu4(z2v[j4]);

  float o0 = bm3S[0], o1 = bm3S[1];
#pragma unroll
  for (int k4 = 0; k4 < 8; ++k4) {
    float4 fz = z2v[k4];
    float4 wa = ld4(&W3S[k4 * 4]);
    float4 wb = ld4(&W3S[32 + k4 * 4]);
    o0 = fmaf(fz.x, wa.x, o0); o0 = fmaf(fz.y, wa.y, o0);
    o0 = fmaf(fz.z, wa.z, o0); o0 = fmaf(fz.w, wa.w, o0);
    o1 = fmaf(fz.x, wb.x, o1); o1 = fmaf(fz.y, wb.y, o1);
    o1 = fmaf(fz.z, wb.z, o1); o1 = fmaf(fz.w, wb.w, o1);
  }
  *(float2*)&out[(size_t)e * 2] = make_float2(o0, o1);
}

// ---------------- launcher ----------------
extern "C" void kernel_launch(void* const* d_in, const int* in_sizes, int n_in,
                              void* d_out, int out_size, void* d_ws, size_t ws_size,
                              hipStream_t stream) {
  const float* x    = (const float*)d_in[0];
  const int*   ei   = (const int*)d_in[1];
  const float* ea   = (const float*)d_in[2];
  const int*   tix  = (const int*)d_in[3];
  const float* temb = (const float*)d_in[4];
  const float* W1l  = (const float*)d_in[5];
  const float* b1l  = (const float*)d_in[6];
  const float* W1r  = (const float*)d_in[7];
  const float* g1   = (const float*)d_in[8];
  const float* be1  = (const float*)d_in[9];
  const float* W2l  = (const float*)d_in[10];
  const float* b2l  = (const float*)d_in[11];
  const float* W2r  = (const float*)d_in[12];
  const float* g2   = (const float*)d_in[13];
  const float* be2  = (const float*)d_in[14];
  const float* Wm1  = (const float*)d_in[15];
  const float* bm1  = (const float*)d_in[16];
  const float* Wm2  = (const float*)d_in[17];
  const float* bm2  = (const float*)d_in[18];
  const float* Wm3  = (const float*)d_in[19];
  const float* bm3  = (const float*)d_in[20];
  float* out = (float*)d_out;

  const int N = in_sizes[0] / 128;
  const int E = in_sizes[3];

  char* w = (char*)d_ws;
  auto alloc = [&](size_t bytes) -> char* {
    char* p = w;
    w += (bytes + 255) & ~(size_t)255;
    return p;
  };
  int* deg      = (int*)alloc((size_t)N * 4);
  int* off      = (int*)alloc((size_t)(N + 1) * 4);
  int* cur      = (int*)alloc((size_t)N * 4);
  int* elist    = (int*)alloc((size_t)E * 4);
  float* P      = (float*)alloc((size_t)N * 128 * 4);  // also reused as UV
  float* HP     = (float*)alloc((size_t)N * 64 * 4);   // hpre1 then hpre2
  float* partials = (float*)alloc(256 * 128 * 4);
  float* sc1 = (float*)alloc(64 * 4);
  float* sh1 = (float*)alloc(64 * 4);
  float* sc2 = (float*)alloc(64 * 4);
  float* sh2 = (float*)alloc(64 * 4);
  float* Dte = (float*)alloc(16 * 64 * 4);
  int* bsum  = (int*)alloc(256 * 4);

  const int* srcp = ei;
  const int* dstp = ei + E;

  int eb = (E + 255) / 256;
  int nb4 = (N + 3) / 4;
  int nb64 = (N + 63) / 64;
  int sb = (N + 1023) / 1024;

  // CSR build (shared by both SAGE layers)
  hipMemsetAsync(deg, 0, (size_t)N * 4, stream);
  hipLaunchKernelGGL(hist_kernel, dim3(eb), dim3(256), 0, stream, dstp, E, deg);
  hipLaunchKernelGGL(scan_blocks_kernel, dim3(sb), dim3(1024), 0, stream, deg, N, off, bsum);
  hipLaunchKernelGGL(scan_sums_kernel, dim3(1), dim3(64), 0, stream, bsum, sb);
  hipLaunchKernelGGL(scan_add_kernel, dim3(sb), dim3(1024), 0, stream, bsum, N, off, cur);
  hipLaunchKernelGGL(fill_kernel, dim3(eb), dim3(256), 0, stream, srcp, dstp, E, cur, elist);

  // ---- SAGE layer 1 ----
  hipLaunchKernelGGL((proj2_kernel<128, false>), dim3(nb64, 2), dim3(256), 0, stream,
                     x, W1l, 128, 0, W1r, 128, 0, (const float*)nullptr, (const float*)nullptr, P, N);
  hipLaunchKernelGGL(agg_kernel, dim3(nb4), dim3(256), 0, stream, P, off, deg, elist, b1l, HP, N);
  hipLaunchKernelGGL(stats_kernel, dim3(256), dim3(256), 0, stream, HP, N, partials);
  hipLaunchKernelGGL(bn_finalize_kernel, dim3(1), dim3(64), 0, stream, partials, 256, N, g1, be1, sc1, sh1);

  // ---- SAGE layer 2 (BN1+relu fused into projection load) ----
  hipLaunchKernelGGL((proj2_kernel<64, true>), dim3(nb64, 2), dim3(256), 0, stream,
                     HP, W2l, 64, 0, W2r, 64, 0, sc1, sh1, P, N);
  hipLaunchKernelGGL(agg_kernel, dim3(nb4), dim3(256), 0, stream, P, off, deg, elist, b2l, HP, N);
  hipLaunchKernelGGL(stats_kernel, dim3(256), dim3(256), 0, stream, HP, N, partials);
  hipLaunchKernelGGL(bn_finalize_kernel, dim3(1), dim3(64), 0, stream, partials, 256, N, g2, be2, sc2, sh2);

  // ---- u/v node precompute: u = Wm1[:, :64] @ h2, v = Wm1[:, 64:128] @ h2 ----
  hipLaunchKernelGGL((proj2_kernel<64, true>), dim3(nb64, 2), dim3(256), 0, stream,
                     HP, Wm1, 152, 0, Wm1, 152, 64, sc2, sh2, P, N);
  hipLaunchKernelGGL(dte_kernel, dim3(1), dim3(1024), 0, stream, Wm1, temb, bm1, Dte);

  // ---- fused edge MLP ----
  hipLaunchKernelGGL(edge_kernel, dim3(eb), dim3(256), 0, stream,
                     P, ei, ea, tix, Dte, Wm1, Wm2, bm2, Wm3, bm3, out, E);
}

// Round 3
// 781.833 us; speedup vs baseline: 1.9601x; 1.1140x over previous
//
#include <hip/hip_runtime.h>

constexpr float BN_EPS = 1e-5f;

__device__ __forceinline__ float4 ld4(const float* p) { return *(const float4*)p; }
__device__ __forceinline__ void fma4(float4& a, const float4 w, const float f) {
  a.x = fmaf(w.x, f, a.x); a.y = fmaf(w.y, f, a.y);
  a.z = fmaf(w.z, f, a.z); a.w = fmaf(w.w, f, a.w);
}
__device__ __forceinline__ void relu4(float4& a) {
  a.x = fmaxf(a.x, 0.f); a.y = fmaxf(a.y, 0.f);
  a.z = fmaxf(a.z, 0.f); a.w = fmaxf(a.w, 0.f);
}
__device__ __forceinline__ unsigned short f2bf(float x) {
  union { float f; unsigned u; } c; c.f = x;
  unsigned r = (c.u + 0x7fffu + ((c.u >> 16) & 1u)) >> 16;
  return (unsigned short)r;
}
__device__ __forceinline__ float bf1(unsigned short h) {
  union { unsigned i; float f; } a; a.i = ((unsigned)h) << 16; return a.f;
}
__device__ __forceinline__ float2 bf2(unsigned u) {
  union { unsigned i; float f; } lo, hi;
  lo.i = u << 16; hi.i = u & 0xffff0000u;
  return make_float2(lo.f, hi.f);
}

// ---------------- CSR build ----------------
__global__ void hist_kernel(const int* __restrict__ dst, int E, int* __restrict__ deg) {
  int e = blockIdx.x * 256 + threadIdx.x;
  if (e < E) atomicAdd(&deg[dst[e]], 1);
}

__global__ __launch_bounds__(1024) void scan_blocks_kernel(const int* __restrict__ deg, int n,
                                                           int* __restrict__ off, int* __restrict__ bsum) {
  __shared__ int lds[1024];
  int i = blockIdx.x * 1024 + threadIdx.x;
  int v = (i < n) ? deg[i] : 0;
  lds[threadIdx.x] = v;
  __syncthreads();
  for (int s = 1; s < 1024; s <<= 1) {
    int t = (threadIdx.x >= (unsigned)s) ? lds[threadIdx.x - s] : 0;
    __syncthreads();
    lds[threadIdx.x] += t;
    __syncthreads();
  }
  if (i < n) off[i] = lds[threadIdx.x] - v;
  if (threadIdx.x == 1023) bsum[blockIdx.x] = lds[1023];
}

__global__ void scan_sums_kernel(int* __restrict__ bsum, int nb) {
  int carry = 0;
  for (int base = 0; base < nb; base += 64) {
    int l = base + (int)threadIdx.x;
    int orig = (l < nb) ? bsum[l] : 0;
    int v = orig;
    for (int s = 1; s < 64; s <<= 1) {
      int t = __shfl_up(v, s);
      if ((int)threadIdx.x >= s) v += t;
    }
    if (l < nb) bsum[l] = carry + v - orig;
    carry += __shfl(v, 63);
  }
}

__global__ __launch_bounds__(1024) void scan_add_kernel(const int* __restrict__ bsum, int n,
                                                        int* __restrict__ off, int* __restrict__ cur) {
  int i = blockIdx.x * 1024 + threadIdx.x;
  if (i < n) {
    int o = off[i] + bsum[blockIdx.x];
    off[i] = o;
    cur[i] = o;
  }
}

__global__ void fill_kernel(const int* __restrict__ src, const int* __restrict__ dst, int E,
                            int* __restrict__ cur, int* __restrict__ elist) {
  int e = blockIdx.x * 256 + threadIdx.x;
  if (e < E) {
    int p = atomicAdd(&cur[dst[e]], 1);
    elist[p] = src[e];
  }
}

// ---------------- node projection: LDS-tiled GEMM ----------------
// Block tile: 64 nodes x 64 outputs; blockIdx.y = output half (Wa / Wb).
// MODE 0: ob=0 -> bf16 msg table outA[N,64]; ob=1 -> f32 xr table outB[N,64]
// MODE 1: both halves -> bf16 outA[N,128] at col ob*64 + ...
template <int K, bool BN, int MODE>
__global__ __launch_bounds__(256) void proj2_kernel(
    const float* __restrict__ X,
    const float* __restrict__ Wa, int lda, int koffa,
    const float* __restrict__ Wb, int ldb, int koffb,
    const float* __restrict__ scale, const float* __restrict__ shift,
    void* __restrict__ outA, void* __restrict__ outB, int n) {
  constexpr int KP = K + 4;
  __shared__ alignas(16) float ws[64 * KP];
  __shared__ alignas(16) float xs[64 * KP];
  const int ob = blockIdx.y;
  const float* W = ob ? Wb : Wa;
  const int ld = ob ? ldb : lda;
  const int koff = ob ? koffb : koffa;

  for (int idx = threadIdx.x; idx < 64 * K; idx += 256) {
    int o = idx / K, k = idx - o * K;
    ws[o * KP + k] = W[o * ld + koff + k];
  }
  int nb = blockIdx.x * 64;
  for (int idx = threadIdx.x; idx < 64 * K; idx += 256) {
    int nl = idx / K, k = idx - nl * K;
    int node = nb + nl;
    float v = (node < n) ? X[(size_t)node * K + k] : 0.f;
    if (BN) v = fmaxf(fmaf(v, scale[k], shift[k]), 0.f);
    xs[nl * KP + k] = v;
  }
  __syncthreads();

  int ng = threadIdx.x >> 4;
  int og = threadIdx.x & 15;
  float acc[4][4];
#pragma unroll
  for (int i = 0; i < 4; ++i)
#pragma unroll
    for (int j = 0; j < 4; ++j) acc[i][j] = 0.f;

  const float* xp = xs + (ng * 4) * KP;
  const float* wp = ws + og * KP;
#pragma unroll 2
  for (int k4 = 0; k4 < K / 4; ++k4) {
    float4 xv[4];
#pragma unroll
    for (int i = 0; i < 4; ++i) xv[i] = ld4(xp + i * KP + k4 * 4);
#pragma unroll
    for (int j = 0; j < 4; ++j) {
      float4 wv = ld4(wp + (j * 16) * KP + k4 * 4);
#pragma unroll
      for (int i = 0; i < 4; ++i) {
        acc[i][j] = fmaf(xv[i].x, wv.x, acc[i][j]);
        acc[i][j] = fmaf(xv[i].y, wv.y, acc[i][j]);
        acc[i][j] = fmaf(xv[i].z, wv.z, acc[i][j]);
        acc[i][j] = fmaf(xv[i].w, wv.w, acc[i][j]);
      }
    }
  }

#pragma unroll
  for (int i = 0; i < 4; ++i) {
    int node = nb + ng * 4 + i;
    if (node < n) {
#pragma unroll
      for (int j = 0; j < 4; ++j) {
        int col = j * 16 + og;
        float v = acc[i][j];
        if (MODE == 0) {
          if (ob == 0) ((unsigned short*)outA)[(size_t)node * 64 + col] = f2bf(v);
          else         ((float*)outB)[(size_t)node * 64 + col] = v;
        } else {
          ((unsigned short*)outA)[(size_t)node * 128 + ob * 64 + col] = f2bf(v);
        }
      }
    }
  }
}

// ---------------- aggregation: HP[i][c] = mean_{s in N(i)} Pm[s][c] + bl[c] + Xr[i][c] ----
__global__ __launch_bounds__(256) void agg_kernel(
    const unsigned short* __restrict__ Pm, const float* __restrict__ Xr,
    const int* __restrict__ off, const int* __restrict__ deg,
    const int* __restrict__ elist, const float* __restrict__ bl,
    float* __restrict__ HP, int n) {
  int node = blockIdx.x * 4 + (threadIdx.x >> 6);
  if (node >= n) return;
  int c = threadIdx.x & 63;
  int d = deg[node];
  int o = off[node];
  float a0 = 0.f, a1 = 0.f, a2 = 0.f, a3 = 0.f;
  float a4 = 0.f, a5 = 0.f, a6 = 0.f, a7 = 0.f;
  int j = 0;
  for (; j + 8 <= d; j += 8) {
    int s0 = elist[o + j + 0], s1 = elist[o + j + 1], s2 = elist[o + j + 2], s3 = elist[o + j + 3];
    int s4 = elist[o + j + 4], s5 = elist[o + j + 5], s6 = elist[o + j + 6], s7 = elist[o + j + 7];
    a0 += bf1(Pm[(size_t)s0 * 64 + c]);
    a1 += bf1(Pm[(size_t)s1 * 64 + c]);
    a2 += bf1(Pm[(size_t)s2 * 64 + c]);
    a3 += bf1(Pm[(size_t)s3 * 64 + c]);
    a4 += bf1(Pm[(size_t)s4 * 64 + c]);
    a5 += bf1(Pm[(size_t)s5 * 64 + c]);
    a6 += bf1(Pm[(size_t)s6 * 64 + c]);
    a7 += bf1(Pm[(size_t)s7 * 64 + c]);
  }
  for (; j < d; ++j) a0 += bf1(Pm[(size_t)elist[o + j] * 64 + c]);
  float acc = ((a0 + a1) + (a2 + a3)) + ((a4 + a5) + (a6 + a7));
  float agg = acc / (float)(d > 0 ? d : 1);
  HP[(size_t)node * 64 + c] = agg + bl[c] + Xr[(size_t)node * 64 + c];
}

// ---------------- BN statistics ----------------
__global__ __launch_bounds__(256) void stats_kernel(const float* __restrict__ HP, int n,
                                                    float* __restrict__ partials) {
  int c = threadIdx.x & 63;
  int r0 = blockIdx.x * 4 + (threadIdx.x >> 6);
  float s = 0.f, q = 0.f;
  for (int i = r0; i < n; i += 1024) {
    float v = HP[(size_t)i * 64 + c];
    s += v; q += v * v;
  }
  __shared__ float ls[256], lq[256];
  ls[threadIdx.x] = s; lq[threadIdx.x] = q;
  __syncthreads();
  if (threadIdx.x < 64) {
    s = ls[threadIdx.x] + ls[threadIdx.x + 64] + ls[threadIdx.x + 128] + ls[threadIdx.x + 192];
    q = lq[threadIdx.x] + lq[threadIdx.x + 64] + lq[threadIdx.x + 128] + lq[threadIdx.x + 192];
    partials[blockIdx.x * 128 + c] = s;
    partials[blockIdx.x * 128 + 64 + c] = q;
  }
}

__global__ void bn_finalize_kernel(const float* __restrict__ partials, int nblk, int n,
                                   const float* __restrict__ g, const float* __restrict__ be,
                                   float* __restrict__ scale, float* __restrict__ shift) {
  int c = threadIdx.x;  // 64 threads
  float s = 0.f, q = 0.f;
  for (int b = 0; b < nblk; ++b) { s += partials[b * 128 + c]; q += partials[b * 128 + 64 + c]; }
  float mean = s / (float)n;
  float var = q / (float)n - mean * mean;
  float sc = g[c] * rsqrtf(var + BN_EPS);
  scale[c] = sc;
  shift[c] = be[c] - mean * sc;
}

// ---------------- Dte[t][o] = bm1[o] + sum_k Wm1[o][144+k]*temb[t][k] ----------------
__global__ void dte_kernel(const float* __restrict__ Wm1, const float* __restrict__ temb,
                           const float* __restrict__ bm1, float* __restrict__ Dte) {
  int t = threadIdx.x >> 6, o = threadIdx.x & 63;  // 1024 threads
  float acc = bm1[o];
#pragma unroll
  for (int k = 0; k < 8; ++k) acc = fmaf(Wm1[o * 152 + 144 + k], temb[t * 8 + k], acc);
  Dte[t * 64 + o] = acc;
}

// ---------------- fused edge MLP ----------------
__global__ __launch_bounds__(256) void edge_kernel(
    const unsigned short* __restrict__ UVb, const int* __restrict__ ei,
    const float* __restrict__ eattr, const int* __restrict__ tix,
    const float* __restrict__ Dte,
    const float* __restrict__ Wm1, const float* __restrict__ Wm2,
    const float* __restrict__ bm2, const float* __restrict__ Wm3,
    const float* __restrict__ bm3, float* __restrict__ out, int E) {
  __shared__ alignas(16) float CwT[16][64];    // Wm1[:,128:144] transposed
  __shared__ alignas(16) float W2T[64][32];    // Wm2 transposed
  __shared__ alignas(16) float DteS[16 * 68];  // pitch 68 to spread banks
  __shared__ alignas(16) float W3S[64];
  __shared__ float bm2S[32];
  __shared__ float bm3S[2];
  for (int idx = threadIdx.x; idx < 1024; idx += 256) {
    int k = idx >> 6, o = idx & 63;
    CwT[k][o] = Wm1[o * 152 + 128 + k];
    DteS[k * 68 + o] = Dte[idx];
  }
  for (int idx = threadIdx.x; idx < 2048; idx += 256) {
    int k = idx >> 5, jj = idx & 31;
    W2T[k][jj] = Wm2[jj * 64 + k];
  }
  if (threadIdx.x < 64) W3S[threadIdx.x] = Wm3[threadIdx.x];
  if (threadIdx.x < 32) bm2S[threadIdx.x] = bm2[threadIdx.x];
  if (threadIdx.x < 2) bm3S[threadIdx.x] = bm3[threadIdx.x];
  __syncthreads();

  int e = blockIdx.x * 256 + threadIdx.x;
  if (e >= E) return;
  int s = ei[e], d = ei[E + e], t = tix[e];

  float ea[16];
#pragma unroll
  for (int q = 0; q < 4; ++q) {
    float4 v = ld4(&eattr[(size_t)e * 16 + q * 4]);
    ea[q * 4 + 0] = v.x; ea[q * 4 + 1] = v.y; ea[q * 4 + 2] = v.z; ea[q * 4 + 3] = v.w;
  }
  const unsigned short* up = UVb + (size_t)s * 128;
  const unsigned short* vp = UVb + (size_t)d * 128 + 64;

  // z1 = u[src] + v[dst] (bf16 gathers), then + Dte[t] + Cw @ ea
  float4 z1v[16];
#pragma unroll
  for (int q = 0; q < 8; ++q) {
    uint4 a = *(const uint4*)(up + q * 8);
    uint4 b = *(const uint4*)(vp + q * 8);
    float2 ax = bf2(a.x), ay = bf2(a.y), az = bf2(a.z), aw = bf2(a.w);
    float2 bx = bf2(b.x), by = bf2(b.y), bz = bf2(b.z), bw = bf2(b.w);
    z1v[2 * q]     = make_float4(ax.x + bx.x, ax.y + bx.y, ay.x + by.x, ay.y + by.y);
    z1v[2 * q + 1] = make_float4(az.x + bz.x, az.y + bz.y, aw.x + bw.x, aw.y + bw.y);
  }
#pragma unroll
  for (int o4 = 0; o4 < 16; ++o4) {
    float4 dd = ld4(&DteS[t * 68 + o4 * 4]);
    z1v[o4].x += dd.x; z1v[o4].y += dd.y; z1v[o4].z += dd.z; z1v[o4].w += dd.w;
  }
#pragma unroll
  for (int k = 0; k < 16; ++k) {
    float f = ea[k];
#pragma unroll
    for (int o4 = 0; o4 < 16; ++o4) {
      float4 wv = ld4(&CwT[k][o4 * 4]);
      fma4(z1v[o4], wv, f);
    }
  }
#pragma unroll
  for (int o4 = 0; o4 < 16; ++o4) relu4(z1v[o4]);

  float4 z2v[8];
#pragma unroll
  for (int j4 = 0; j4 < 8; ++j4) {
    z2v[j4].x = bm2S[j4 * 4 + 0]; z2v[j4].y = bm2S[j4 * 4 + 1];
    z2v[j4].z = bm2S[j4 * 4 + 2]; z2v[j4].w = bm2S[j4 * 4 + 3];
  }
#pragma unroll
  for (int k4 = 0; k4 < 16; ++k4) {
    float4 fz = z1v[k4];
#pragma unroll
    for (int j4 = 0; j4 < 8; ++j4) {
      float4 w0 = ld4(&W2T[k4 * 4 + 0][j4 * 4]);
      float4 w1 = ld4(&W2T[k4 * 4 + 1][j4 * 4]);
      float4 w2 = ld4(&W2T[k4 * 4 + 2][j4 * 4]);
      float4 w3 = ld4(&W2T[k4 * 4 + 3][j4 * 4]);
      fma4(z2v[j4], w0, fz.x);
      fma4(z2v[j4], w1, fz.y);
      fma4(z2v[j4], w2, fz.z);
      fma4(z2v[j4], w3, fz.w);
    }
  }
#pragma unroll
  for (int j4 = 0; j4 < 8; ++j4) relu4(z2v[j4]);

  float o0 = bm3S[0], o1 = bm3S[1];
#pragma unroll
  for (int k4 = 0; k4 < 8; ++k4) {
    float4 fz = z2v[k4];
    float4 wa = ld4(&W3S[k4 * 4]);
    float4 wb = ld4(&W3S[32 + k4 * 4]);
    o0 = fmaf(fz.x, wa.x, o0); o0 = fmaf(fz.y, wa.y, o0);
    o0 = fmaf(fz.z, wa.z, o0); o0 = fmaf(fz.w, wa.w, o0);
    o1 = fmaf(fz.x, wb.x, o1); o1 = fmaf(fz.y, wb.y, o1);
    o1 = fmaf(fz.z, wb.z, o1); o1 = fmaf(fz.w, wb.w, o1);
  }
  *(float2*)&out[(size_t)e * 2] = make_float2(o0, o1);
}

// ---------------- launcher ----------------
extern "C" void kernel_launch(void* const* d_in, const int* in_sizes, int n_in,
                              void* d_out, int out_size, void* d_ws, size_t ws_size,
                              hipStream_t stream) {
  const float* x    = (const float*)d_in[0];
  const int*   ei   = (const int*)d_in[1];
  const float* ea   = (const float*)d_in[2];
  const int*   tix  = (const int*)d_in[3];
  const float* temb = (const float*)d_in[4];
  const float* W1l  = (const float*)d_in[5];
  const float* b1l  = (const float*)d_in[6];
  const float* W1r  = (const float*)d_in[7];
  const float* g1   = (const float*)d_in[8];
  const float* be1  = (const float*)d_in[9];
  const float* W2l  = (const float*)d_in[10];
  const float* b2l  = (const float*)d_in[11];
  const float* W2r  = (const float*)d_in[12];
  const float* g2   = (const float*)d_in[13];
  const float* be2  = (const float*)d_in[14];
  const float* Wm1  = (const float*)d_in[15];
  const float* bm1  = (const float*)d_in[16];
  const float* Wm2  = (const float*)d_in[17];
  const float* bm2  = (const float*)d_in[18];
  const float* Wm3  = (const float*)d_in[19];
  const float* bm3  = (const float*)d_in[20];
  float* out = (float*)d_out;

  const int N = in_sizes[0] / 128;
  const int E = in_sizes[3];

  char* w = (char*)d_ws;
  auto alloc = [&](size_t bytes) -> char* {
    char* p = w;
    w += (bytes + 255) & ~(size_t)255;
    return p;
  };
  int* deg   = (int*)alloc((size_t)N * 4);
  int* off   = (int*)alloc((size_t)(N + 1) * 4);
  int* cur   = (int*)alloc((size_t)N * 4);
  int* elist = (int*)alloc((size_t)E * 4);
  unsigned short* Pm  = (unsigned short*)alloc((size_t)N * 64 * 2);   // bf16 msg table
  float*          Xr  = (float*)alloc((size_t)N * 64 * 4);            // f32 lin_r part
  unsigned short* UVb = (unsigned short*)alloc((size_t)N * 128 * 2);  // bf16 u|v table
  float* HP       = (float*)alloc((size_t)N * 64 * 4);
  float* partials = (float*)alloc(256 * 128 * 4);
  float* sc1 = (float*)alloc(64 * 4);
  float* sh1 = (float*)alloc(64 * 4);
  float* sc2 = (float*)alloc(64 * 4);
  float* sh2 = (float*)alloc(64 * 4);
  float* Dte = (float*)alloc(16 * 64 * 4);
  int* bsum  = (int*)alloc(256 * 4);

  const int* srcp = ei;
  const int* dstp = ei + E;

  int eb = (E + 255) / 256;
  int nb4 = (N + 3) / 4;
  int nb64 = (N + 63) / 64;
  int sb = (N + 1023) / 1024;

  // CSR build (shared by both SAGE layers)
  hipMemsetAsync(deg, 0, (size_t)N * 4, stream);
  hipLaunchKernelGGL(hist_kernel, dim3(eb), dim3(256), 0, stream, dstp, E, deg);
  hipLaunchKernelGGL(scan_blocks_kernel, dim3(sb), dim3(1024), 0, stream, deg, N, off, bsum);
  hipLaunchKernelGGL(scan_sums_kernel, dim3(1), dim3(64), 0, stream, bsum, sb);
  hipLaunchKernelGGL(scan_add_kernel, dim3(sb), dim3(1024), 0, stream, bsum, N, off, cur);
  hipLaunchKernelGGL(fill_kernel, dim3(eb), dim3(256), 0, stream, srcp, dstp, E, cur, elist);

  // ---- SAGE layer 1 ----
  hipLaunchKernelGGL((proj2_kernel<128, false, 0>), dim3(nb64, 2), dim3(256), 0, stream,
                     x, W1l, 128, 0, W1r, 128, 0, (const float*)nullptr, (const float*)nullptr,
                     (void*)Pm, (void*)Xr, N);
  hipLaunchKernelGGL(agg_kernel, dim3(nb4), dim3(256), 0, stream, Pm, Xr, off, deg, elist, b1l, HP, N);
  hipLaunchKernelGGL(stats_kernel, dim3(256), dim3(256), 0, stream, HP, N, partials);
  hipLaunchKernelGGL(bn_finalize_kernel, dim3(1), dim3(64), 0, stream, partials, 256, N, g1, be1, sc1, sh1);

  // ---- SAGE layer 2 (BN1+relu fused into projection load) ----
  hipLaunchKernelGGL((proj2_kernel<64, true, 0>), dim3(nb64, 2), dim3(256), 0, stream,
                     HP, W2l, 64, 0, W2r, 64, 0, sc1, sh1, (void*)Pm, (void*)Xr, N);
  hipLaunchKernelGGL(agg_kernel, dim3(nb4), dim3(256), 0, stream, Pm, Xr, off, deg, elist, b2l, HP, N);
  hipLaunchKernelGGL(stats_kernel, dim3(256), dim3(256), 0, stream, HP, N, partials);
  hipLaunchKernelGGL(bn_finalize_kernel, dim3(1), dim3(64), 0, stream, partials, 256, N, g2, be2, sc2, sh2);

  // ---- u/v node precompute: u = Wm1[:, :64] @ h2, v = Wm1[:, 64:128] @ h2 ----
  hipLaunchKernelGGL((proj2_kernel<64, true, 1>), dim3(nb64, 2), dim3(256), 0, stream,
                     HP, Wm1, 152, 0, Wm1, 152, 64, sc2, sh2, (void*)UVb, (void*)nullptr, N);
  hipLaunchKernelGGL(dte_kernel, dim3(1), dim3(1024), 0, stream, Wm1, temb, bm1, Dte);

  // ---- fused edge MLP ----
  hipLaunchKernelGGL(edge_kernel, dim3(eb), dim3(256), 0, stream,
                     UVb, ei, ea, tix, Dte, Wm1, Wm2, bm2, Wm3, bm3, out, E);
}